// Round 9
// baseline (339.765 us; speedup 1.0000x reference)
//
#include <hip/hip_runtime.h>

// out[s,n, l*4096 + i*64 + j] = norm_l(i,j) * sum_m c_l[s,n,m,i]*c_l[s,n,m,j]
// norm_l = (2l+1)^-1/2 off-diag, extra 3^-1/2 on diagonal.
// S*N = 24000 pairs, Q=64, output 1.57 GB fp32 -> write-BW bound.
// R9: R8's XCD-chunked swizzle (-3.5%) + persistent blocks (PPB pairs each,
// double-buffered LDS w/ issue-early prefetch). Each CU writes a 768KB
// contiguous stream; each XCD owns one contiguous slab of the output.

#define NTHREADS 256
#define PPB 12
#define NXCD 8

typedef __attribute__((ext_vector_type(4))) float f32x4;

__global__ __launch_bounds__(NTHREADS) void ps_kernel(
    const float* __restrict__ c0, const float* __restrict__ c1,
    const float* __restrict__ c2, const float* __restrict__ c3,
    float* __restrict__ out, int total, int nblocks)
{
    __shared__ float lds[2][16 * 64];  // double-buffered: 16 m-rows x 64 q

    const int t = threadIdx.x;

    // XCD-chunked bijective swizzle over the block range (nblocks % 8 == 0)
    const int bid = blockIdx.x;
    const int blk = (bid & (NXCD - 1)) * (nblocks / NXCD) + (bid / NXCD);

    const int pstart = blk * PPB;
    const int pend   = (pstart + PPB < total) ? (pstart + PPB) : total;
    if (pstart >= total) return;

    // ---- per-thread staging role (fixed across pairs) ----
    const float* src;     // base of source array
    int local;            // f32x4 index within this pair's region
    int ldsoff;           // float offset of region start in lds
    int stride;           // floats per pair in source array
    if (t < 16)       { src = c0; local = t;       ldsoff = 0;   stride = 1 * 64; }
    else if (t < 64)  { src = c1; local = t - 16;  ldsoff = 64;  stride = 3 * 64; }
    else if (t < 144) { src = c2; local = t - 64;  ldsoff = 256; stride = 5 * 64; }
    else              { src = c3; local = t - 144; ldsoff = 576; stride = 7 * 64; }

    const int jq = t & 15;        // j-quad: columns 4*jq .. 4*jq+3
    const int i0 = t >> 4;        // base row 0..15; rows i0 + 16*r, r=0..3
    const int jbase = jq * 4;

    const float INV_SQRT3 = 0.57735026918962576f;
    const float CG[4] = {1.0f, 0.57735026918962576f, 0.44721359549995794f, 0.37796447300922720f};
    const int MOFF[4] = {0, 1, 4, 9};

    // per-thread diagonal fix, independent of l
    f32x4 dfix[4];
    #pragma unroll
    for (int r = 0; r < 4; ++r) {
        const int i = i0 + 16 * r;
        f32x4 d;
        d.x = (i == jbase + 0) ? INV_SQRT3 : 1.0f;
        d.y = (i == jbase + 1) ? INV_SQRT3 : 1.0f;
        d.z = (i == jbase + 2) ? INV_SQRT3 : 1.0f;
        d.w = (i == jbase + 3) ? INV_SQRT3 : 1.0f;
        dfix[r] = d;
    }

    f32x4* outv = reinterpret_cast<f32x4*>(out);

    // prologue: load pair pstart
    f32x4 v = *(reinterpret_cast<const f32x4*>(src + (size_t)pstart * stride) + local);

    int cur = 0;
    for (int p = pstart; p < pend; ++p) {
        *reinterpret_cast<f32x4*>(&lds[cur][ldsoff + local * 4]) = v;
        __syncthreads();

        // issue next pair's load early — hides HBM latency under compute
        if (p + 1 < pend)
            v = *(reinterpret_cast<const f32x4*>(src + (size_t)(p + 1) * stride) + local);

        const float* L = lds[cur];
        const size_t obase4 = (size_t)p * (16384 / 4);

        #pragma unroll
        for (int l = 0; l < 4; ++l) {
            const int nm = 2 * l + 1;
            const int moff = MOFF[l];
            const float cg = CG[l];

            f32x4 cj[7];
            #pragma unroll
            for (int m = 0; m < nm; ++m)
                cj[m] = (*reinterpret_cast<const f32x4*>(&L[(moff + m) * 64 + jbase])) * cg;

            #pragma unroll
            for (int r = 0; r < 4; ++r) {
                const int i = i0 + r * 16;
                f32x4 acc = {0.0f, 0.0f, 0.0f, 0.0f};
                #pragma unroll
                for (int m = 0; m < nm; ++m) {
                    const float ci = L[(moff + m) * 64 + i];  // broadcast in 16-lane group
                    acc += ci * cj[m];
                }
                acc *= dfix[r];
                outv[obase4 + (size_t)l * 1024 + (size_t)i * 16 + jq] = acc;
            }
        }

        cur ^= 1;
        __syncthreads();  // buffer cur reused 2 iters later
    }
}

extern "C" void kernel_launch(void* const* d_in, const int* in_sizes, int n_in,
                              void* d_out, int out_size, void* d_ws, size_t ws_size,
                              hipStream_t stream) {
    const float* c0 = (const float*)d_in[0];
    const float* c1 = (const float*)d_in[1];
    const float* c2 = (const float*)d_in[2];
    const float* c3 = (const float*)d_in[3];
    float* out = (float*)d_out;

    const int total = in_sizes[0] / 64;              // S*N pairs = 24000
    const int nblocks = (total + PPB - 1) / PPB;     // 2000, divisible by 8

    ps_kernel<<<dim3(nblocks), dim3(NTHREADS), 0, stream>>>(c0, c1, c2, c3, out,
                                                            total, nblocks);
}

// Round 10
// 318.085 us; speedup vs baseline: 1.0682x; 1.0682x over previous
//
#include <hip/hip_runtime.h>

// out[s,n, l*4096 + i*64 + j] = norm_l(i,j) * sum_m c_l[s,n,m,i]*c_l[s,n,m,j]
// norm_l = (2l+1)^-1/2 off-diag, extra 3^-1/2 on diagonal.
// S*N = 24000 pairs, Q=64, output 1.57 GB fp32 -> write-BW bound.
// R10 = R8 (best: 317.9us): one pair per block + T1 XCD-chunked block swizzle.
// Each XCD owns a contiguous 1/8 slab of the output -> long-sequential
// per-XCD write streams. Persistence (R4/R9) costs ~+10us; nt stores +8%;
// everything else neutral. 5.26 TB/s combined = 81% of fill-kernel rate.

#define NTHREADS 256
#define NXCD 8

typedef __attribute__((ext_vector_type(4))) float f32x4;

__global__ __launch_bounds__(NTHREADS) void ps_kernel(
    const float* __restrict__ c0, const float* __restrict__ c1,
    const float* __restrict__ c2, const float* __restrict__ c3,
    float* __restrict__ out, int total)
{
    __shared__ float lds[16 * 64];  // 16 m-rows (l0:0, l1:1..3, l2:4..8, l3:9..15) x 64 q

    // XCD-chunked bijective swizzle (total % 8 == 0: 24000 pairs)
    const int bid = blockIdx.x;
    const int blk = (bid & (NXCD - 1)) * (total / NXCD) + (bid / NXCD);
    const int t = threadIdx.x;

    // ---- stage c into LDS: one f32x4 per thread (256 x4 = 1024 floats) ----
    {
        const float* src;
        int local;       // f32x4 index within region
        int ldsbase;     // float index of region start in lds
        if (t < 16)       { src = c0 + (size_t)blk * (1 * 64); local = t;       ldsbase = 0;   }
        else if (t < 64)  { src = c1 + (size_t)blk * (3 * 64); local = t - 16;  ldsbase = 64;  }
        else if (t < 144) { src = c2 + (size_t)blk * (5 * 64); local = t - 64;  ldsbase = 256; }
        else              { src = c3 + (size_t)blk * (7 * 64); local = t - 144; ldsbase = 576; }
        f32x4 v = *(reinterpret_cast<const f32x4*>(src) + local);
        *reinterpret_cast<f32x4*>(&lds[ldsbase + local * 4]) = v;
    }
    __syncthreads();

    const int jq = t & 15;        // j-quad: columns 4*jq .. 4*jq+3
    const int i0 = t >> 4;        // base row 0..15; rows i0 + 16*r, r=0..3
    const int jbase = jq * 4;

    const float INV_SQRT3 = 0.57735026918962576f;
    const float CG[4] = {1.0f, 0.57735026918962576f, 0.44721359549995794f, 0.37796447300922720f};
    const int MOFF[4] = {0, 1, 4, 9};

    // per-thread diagonal fix, independent of l: row i = i0+16r hits the
    // diagonal at component cc iff i == jbase+cc.
    f32x4 dfix[4];
    #pragma unroll
    for (int r = 0; r < 4; ++r) {
        const int i = i0 + 16 * r;
        f32x4 d;
        d.x = (i == jbase + 0) ? INV_SQRT3 : 1.0f;
        d.y = (i == jbase + 1) ? INV_SQRT3 : 1.0f;
        d.z = (i == jbase + 2) ? INV_SQRT3 : 1.0f;
        d.w = (i == jbase + 3) ? INV_SQRT3 : 1.0f;
        dfix[r] = d;
    }

    f32x4* outv = reinterpret_cast<f32x4*>(out);
    const size_t obase4 = (size_t)blk * (16384 / 4);

    #pragma unroll
    for (int l = 0; l < 4; ++l) {
        const int nm = 2 * l + 1;
        const int moff = MOFF[l];
        const float cg = CG[l];

        // column fragment, pre-scaled by cg (packed mul)
        f32x4 cj[7];
        #pragma unroll
        for (int m = 0; m < nm; ++m)
            cj[m] = (*reinterpret_cast<const f32x4*>(&lds[(moff + m) * 64 + jbase])) * cg;

        #pragma unroll
        for (int r = 0; r < 4; ++r) {
            const int i = i0 + r * 16;
            f32x4 acc = {0.0f, 0.0f, 0.0f, 0.0f};
            #pragma unroll
            for (int m = 0; m < nm; ++m) {
                const float ci = lds[(moff + m) * 64 + i];  // broadcast in 16-lane group
                acc += ci * cj[m];                          // packed fma
            }
            acc *= dfix[r];
            outv[obase4 + (size_t)l * 1024 + (size_t)i * 16 + jq] = acc;
        }
    }
}

extern "C" void kernel_launch(void* const* d_in, const int* in_sizes, int n_in,
                              void* d_out, int out_size, void* d_ws, size_t ws_size,
                              hipStream_t stream) {
    const float* c0 = (const float*)d_in[0];
    const float* c1 = (const float*)d_in[1];
    const float* c2 = (const float*)d_in[2];
    const float* c3 = (const float*)d_in[3];
    float* out = (float*)d_out;

    const int total = in_sizes[0] / 64;  // S*N pairs (c0 is (S,N,1,64)) = 24000

    ps_kernel<<<dim3(total), dim3(NTHREADS), 0, stream>>>(c0, c1, c2, c3, out, total);
}